// Round 6
// baseline (200.780 us; speedup 1.0000x reference)
//
#include <hip/hip_runtime.h>
#include <math.h>

#define FREQ_DIM 256
#define TDIM 512
#define MODC 352
#define EPS 1e-5f

__device__ __forceinline__ float silu_f(float x) {
    return x / (1.0f + expf(-x));
}

// One MLP layer for R rows resident in LDS. T=1024 threads:
// 128 col-groups (4 cols each, float4 w loads) x KS=8 k-slices.
// 2-deep software prefetch of weight chunks (wA/wB). Split-k partials
// reduced via s_acc in LDS. Ends with __syncthreads().
template <int K, int NC, int R, bool POST_SILU, bool TO_GLOBAL>
__device__ __forceinline__ void stage(const float* s_in,              // [R][TDIM]
                                      const float* __restrict__ w,    // [K][NC]
                                      const float* __restrict__ bias, // [NC]
                                      float* outp,                    // LDS [R][TDIM] or global [R][NC]
                                      float* s_acc,                   // [KS][R][512]
                                      int tid) {
    constexpr int KS = 8, KC = K / KS;   // K=512 -> 64, K=256 -> 32
    int c4 = tid & 127;
    int ks = tid >> 7;                   // wave-uniform (2 waves per slice)
    int j0 = 4 * c4;
    int jj = (j0 <= NC - 4) ? j0 : (NC - 4);   // clamp for NC=352 tail (16B aligned)
    const float* wp = w + jj;

    float4 acc[R];
#pragma unroll
    for (int r = 0; r < R; ++r) acc[r] = make_float4(0.f, 0.f, 0.f, 0.f);

    int kbeg = ks * KC, kend = kbeg + KC;

    // 2-deep pipeline: wA = chunk k, wB = chunk k+4 (4 weight rows each)
    float4 wA[4], wB[4];
#pragma unroll
    for (int u = 0; u < 4; ++u) wA[u] = *(const float4*)(wp + (size_t)(kbeg + u) * NC);
#pragma unroll
    for (int u = 0; u < 4; ++u) wB[u] = *(const float4*)(wp + (size_t)(kbeg + 4 + u) * NC);

#pragma unroll 1
    for (int k = kbeg; k < kend; k += 8) {
        // ---- chunk k..k+3: consume wA, prefetch chunk k+8 into wA
        float4 wc[4];
#pragma unroll
        for (int u = 0; u < 4; ++u) wc[u] = wA[u];
        int kp = (k + 12 <= kend) ? (k + 8) : kbeg;   // clamped tail (redundant reload)
#pragma unroll
        for (int u = 0; u < 4; ++u) wA[u] = *(const float4*)(wp + (size_t)(kp + u) * NC);

        float4 sa[R];
#pragma unroll
        for (int r = 0; r < R; ++r) sa[r] = *(const float4*)(s_in + r * TDIM + k);
#pragma unroll
        for (int kk = 0; kk < 4; ++kk) {
#pragma unroll
            for (int r = 0; r < R; ++r) {
                float s = (&sa[r].x)[kk];
                acc[r].x += s * wc[kk].x;
                acc[r].y += s * wc[kk].y;
                acc[r].z += s * wc[kk].z;
                acc[r].w += s * wc[kk].w;
            }
        }

        // ---- chunk k+4..k+7: consume wB, prefetch chunk k+12 into wB
#pragma unroll
        for (int u = 0; u < 4; ++u) wc[u] = wB[u];
        int kp2 = (k + 16 <= kend) ? (k + 12) : kbeg;
#pragma unroll
        for (int u = 0; u < 4; ++u) wB[u] = *(const float4*)(wp + (size_t)(kp2 + u) * NC);

#pragma unroll
        for (int r = 0; r < R; ++r) sa[r] = *(const float4*)(s_in + r * TDIM + k + 4);
#pragma unroll
        for (int kk = 0; kk < 4; ++kk) {
#pragma unroll
            for (int r = 0; r < R; ++r) {
                float s = (&sa[r].x)[kk];
                acc[r].x += s * wc[kk].x;
                acc[r].y += s * wc[kk].y;
                acc[r].z += s * wc[kk].z;
                acc[r].w += s * wc[kk].w;
            }
        }
    }

    // partials at UNCLAMPED j0 (cols >= NC hold junk, never read back)
    float* pa = s_acc + (size_t)(ks * R) * 512;
#pragma unroll
    for (int r = 0; r < R; ++r) *(float4*)(pa + r * 512 + j0) = acc[r];
    __syncthreads();

    for (int o = tid; o < R * NC; o += 1024) {
        int r = o / NC, c = o - r * NC;
        float v = 0.f;
#pragma unroll
        for (int s = 0; s < KS; ++s) v += s_acc[(size_t)(s * R + r) * 512 + c];
        v += bias[c];
        if (POST_SILU) v = silu_f(v);
        if (TO_GLOBAL) outp[(size_t)r * NC + c] = v;
        else           outp[r * TDIM + c] = v;
    }
    __syncthreads();
}

// Fused time-embedding MLP: emb -> silu(.@w1+b1) -> silu(.@w2+b2) -> .@wm+bm
// (trailing silu folded into stage-2's write per reference: mod = silu(t_emb)@wm+bm)
template <int R>
__global__ __launch_bounds__(1024, 4) void k_mlp(const float* __restrict__ t,
                                                 const float* __restrict__ w1, const float* __restrict__ b1,
                                                 const float* __restrict__ w2, const float* __restrict__ b2,
                                                 const float* __restrict__ wm, const float* __restrict__ bm,
                                                 float* __restrict__ mb) {
    __shared__ __align__(16) float s_x[R * TDIM];      // 8 KB
    __shared__ __align__(16) float s_y[R * TDIM];      // 8 KB
    __shared__ __align__(16) float s_acc[8 * R * 512]; // 64 KB
    __shared__ float s_t[R];

    int tid = threadIdx.x;
    int row0 = blockIdx.x * R;

    if (tid < R) s_t[tid] = t[row0 + tid];
    __syncthreads();

    // timestep embedding into s_x[r][0..255] — exactly one element per thread
    const float lm = 9.210340371976184f;   // ln(10000)
    {
        int r = tid >> 8, j = tid & 255;
        int h = j & 127;
        float freq = expf(-lm * (float)h * (1.0f / 128.0f));
        float arg = s_t[r] * freq;
        s_x[r * TDIM + j] = (j < 128) ? cosf(arg) : sinf(arg);
    }
    __syncthreads();

    stage<FREQ_DIM, TDIM, R, true,  false>(s_x, w1, b1, s_y, s_acc, tid);
    stage<TDIM,     TDIM, R, true,  false>(s_y, w2, b2, s_x, s_acc, tid);
    stage<TDIM,     MODC, R, false, true >(s_x, wm, bm, mb + (size_t)row0 * MODC, s_acc, tid);
}

// One wave (64 lanes) per node. Row = 480 f32 = 120 float4.
// float4 idx:  0..31 -> seg0 (layernorm, floats 0..127)
//             32..79 -> seg1 (floats 128..319, 192 elems)
//             80..119-> seg2 (floats 320..479, 160 elems)
__global__ __launch_bounds__(256) void k_main(const float* __restrict__ x,
                                              const int* __restrict__ batch,
                                              const float* __restrict__ mod,
                                              float* __restrict__ out, int N) {
    int node = blockIdx.x * 4 + (threadIdx.x >> 6);
    if (node >= N) return;
    int lane = threadIdx.x & 63;

    const float4* rp = (const float4*)(x + (size_t)node * 480);
    float4 a = rp[lane];                         // f4 idx lane (0..63)
    float4 c = make_float4(0.f, 0.f, 0.f, 0.f);
    if (lane < 56) c = rp[64 + lane];            // f4 idx 64..119

    float s0 = 0.f, q0 = 0.f, q1 = 0.f, q2 = 0.f;
    float da = a.x * a.x + a.y * a.y + a.z * a.z + a.w * a.w;
    if (lane < 32) { s0 = a.x + a.y + a.z + a.w; q0 = da; }
    else           { q1 = da; }
    float dc = c.x * c.x + c.y * c.y + c.z * c.z + c.w * c.w;
    if (lane < 16)      q1 += dc;
    else if (lane < 56) q2 = dc;

#pragma unroll
    for (int m = 1; m < 64; m <<= 1) {
        s0 += __shfl_xor(s0, m, 64);
        q0 += __shfl_xor(q0, m, 64);
        q1 += __shfl_xor(q1, m, 64);
        q2 += __shfl_xor(q2, m, 64);
    }

    int b = batch[node];
    const float* mrow = mod + (size_t)b * MODC;
    float4 m4 = *(const float4*)mrow;            // cols 0..3 (need 0,1,2)

    float mean = s0 * (1.0f / 128.0f);
    float var  = q0 * (1.0f / 128.0f) - mean * mean;
    float r0 = rsqrtf(var + EPS) * (1.0f + m4.x);
    float r1 = rsqrtf(q1 * (1.0f / 192.0f) + EPS) * (1.0f + m4.y);
    float r2 = rsqrtf(q2 * (1.0f / 160.0f) + EPS) * (1.0f + m4.z);

    float4* op = (float4*)(out + (size_t)node * 480);
    float4 o;
    if (lane < 32) {
        float4 sh = *(const float4*)(mrow + 224 + 4 * lane);
        o.x = (a.x - mean) * r0 + sh.x;
        o.y = (a.y - mean) * r0 + sh.y;
        o.z = (a.z - mean) * r0 + sh.z;
        o.w = (a.w - mean) * r0 + sh.w;
    } else {
        o.x = a.x * r1; o.y = a.y * r1; o.z = a.z * r1; o.w = a.w * r1;
    }
    op[lane] = o;
    if (lane < 56) {
        float rr = (lane < 16) ? r1 : r2;
        float4 o2;
        o2.x = c.x * rr; o2.y = c.y * rr; o2.z = c.z * rr; o2.w = c.w * rr;
        op[64 + lane] = o2;
    }
}

extern "C" void kernel_launch(void* const* d_in, const int* in_sizes, int n_in,
                              void* d_out, int out_size, void* d_ws, size_t ws_size,
                              hipStream_t stream) {
    const float* node_input = (const float*)d_in[0];
    const float* t          = (const float*)d_in[1];
    const int*   batch      = (const int*)d_in[2];
    const float* w1         = (const float*)d_in[3];
    const float* b1         = (const float*)d_in[4];
    const float* w2         = (const float*)d_in[5];
    const float* b2         = (const float*)d_in[6];
    const float* wm         = (const float*)d_in[7];
    const float* bm         = (const float*)d_in[8];
    float* out = (float*)d_out;

    int N = in_sizes[0] / 480;   // 100000
    int B = in_sizes[1];         // 1024

    float* mb = (float*)d_ws;    // B*352 f32

    constexpr int R = 4;
    k_mlp<R><<<B / R, 1024, 0, stream>>>(t, w1, b1, w2, b2, wm, bm, mb);
    k_main<<<(N + 3) / 4, 256, 0, stream>>>(node_input, batch, mb, out, N);
}